// Round 1
// baseline (177.562 us; speedup 1.0000x reference)
//
#include <hip/hip_runtime.h>
#include <hip/hip_bf16.h>
#include <math.h>

// Problem constants: B=16, C=128, M=H*W=1024.
#define NB 16
#define NC 128
#define NM 1024

// Persistent device scratch (fully rewritten every call -> deterministic).
__device__ float    g_T[2][NB * NM * NC];     // token-major copies: T[mat][b][p][c]
__device__ float    g_norm[2][NB * NM];       // ||token||^2 per matrix
__device__ unsigned g_idx[2][NB * NM];        // [0]=idx1 (NN of m1 in m2), [1]=idx2
__device__ float    g_part[3][NM];            // per-position partials: R, S, Qraw

// ---------------------------------------------------------------------------
// Transpose E[b][c][p] (c-major) -> T[b][p][c] (token-major), both matrices.
// grid (16 p-tiles, 2 c-tiles, 32 = b*2+mat), block 256.
__global__ __launch_bounds__(256)
void transpose_kernel(const float* __restrict__ e1, const float* __restrict__ e2)
{
    __shared__ float tile[64][65];
    const int z   = blockIdx.z;
    const int b   = z >> 1;
    const int mat = z & 1;
    const float* src = mat ? e2 : e1;
    float*       dst = g_T[mat];
    const int p0 = blockIdx.x * 64;
    const int c0 = blockIdx.y * 64;
    const int tj = threadIdx.x & 63;
    const int ti = threadIdx.x >> 6;     // 0..3
    const float* sb = src + (size_t)b * NC * NM;
    #pragma unroll
    for (int i = 0; i < 16; ++i) {
        int c = i * 4 + ti;
        tile[c][tj] = sb[(size_t)(c0 + c) * NM + p0 + tj];
    }
    __syncthreads();
    float* db = dst + (size_t)b * NM * NC;
    #pragma unroll
    for (int i = 0; i < 16; ++i) {
        int p = i * 4 + ti;
        db[(size_t)(p0 + p) * NC + c0 + tj] = tile[tj][p];
    }
}

// ---------------------------------------------------------------------------
// Token norms directly from the c-major layout (coalesced over p).
// grid 128 = 2 mats * 16 b * 4 p-chunks, block 256.
__global__ __launch_bounds__(256)
void norm_kernel(const float* __restrict__ e1, const float* __restrict__ e2)
{
    const int z   = blockIdx.x;
    const int mat = z >> 6;
    const int b   = (z >> 2) & 15;
    const int pc  = z & 3;
    const float* src = mat ? e2 : e1;
    const int p = pc * 256 + threadIdx.x;
    const float* sb = src + (size_t)b * NC * NM + p;
    float s = 0.f;
    #pragma unroll 4
    for (int c = 0; c < NC; ++c) {
        float v = sb[(size_t)c * NM];
        s += v * v;
    }
    g_norm[mat][b * NM + p] = s;
}

// ---------------------------------------------------------------------------
// Argmin kernel: for each (b, m) of A, argmin over n of ||A[m]-B[n]||^2,
// computed as nB[n] - 2*dot (row-constant ||A[m]||^2 dropped).
// dir 0: A=m1,B=m2 -> idx1 ; dir 1: A=m2,B=m1 -> idx2.
// 64x64 tiles, 4x4 micro-tile, LDS layout [k][row] (conflict-free b128 reads,
// native for the c-major global layout). LDS = 64 KB exactly.
__global__ __launch_bounds__(256, 2)
void argmin_kernel(const float* __restrict__ e1, const float* __restrict__ e2)
{
    __shared__ float lA[NC * 64];
    __shared__ float lB[NC * 64];
    const int dir = blockIdx.y;
    const float* A  = dir ? e2 : e1;
    const float* B  = dir ? e1 : e2;
    const float* nB = g_norm[1 - dir];
    unsigned*   out = g_idx[dir];
    const int b  = blockIdx.x >> 4;
    const int m0 = (blockIdx.x & 15) << 6;
    const int t  = threadIdx.x;
    const int tx = t & 15, ty = t >> 4;
    const float* Ab = A + (size_t)b * NC * NM;
    const float* Bb = B + (size_t)b * NC * NM;

    // Stage A tile: lA[k*64 + r] = A[b][k][m0+r], float4 along r.
    #pragma unroll
    for (int i = 0; i < 8; ++i) {
        int idx = t + i * 256;          // 0..2047 float4-chunks
        int k = idx >> 4, rq = idx & 15;
        float4 v = *reinterpret_cast<const float4*>(Ab + (size_t)k * NM + m0 + rq * 4);
        *reinterpret_cast<float4*>(&lA[k * 64 + rq * 4]) = v;
    }

    float    runv[4];
    unsigned runi[4];
    #pragma unroll
    for (int i = 0; i < 4; ++i) { runv[i] = 3.4e38f; runi[i] = 0u; }

    for (int nt = 0; nt < 16; ++nt) {
        __syncthreads();                 // protect lB (and cover lA staging)
        #pragma unroll
        for (int i = 0; i < 8; ++i) {
            int idx = t + i * 256;
            int k = idx >> 4, rq = idx & 15;
            float4 v = *reinterpret_cast<const float4*>(Bb + (size_t)k * NM + nt * 64 + rq * 4);
            *reinterpret_cast<float4*>(&lB[k * 64 + rq * 4]) = v;
        }
        __syncthreads();

        float acc[4][4] = {};
        #pragma unroll 4
        for (int k = 0; k < NC; ++k) {
            float4 av = *reinterpret_cast<const float4*>(&lA[k * 64 + ty * 4]);
            float4 bv = *reinterpret_cast<const float4*>(&lB[k * 64 + tx * 4]);
            float a4[4] = {av.x, av.y, av.z, av.w};
            float b4[4] = {bv.x, bv.y, bv.z, bv.w};
            #pragma unroll
            for (int i = 0; i < 4; ++i)
                #pragma unroll
                for (int j = 0; j < 4; ++j)
                    acc[i][j] += a4[i] * b4[j];
        }
        // distances + running row minima (n ascending within thread)
        #pragma unroll
        for (int j = 0; j < 4; ++j) {
            int n = nt * 64 + tx * 4 + j;
            float nv = nB[b * NM + n];
            #pragma unroll
            for (int i = 0; i < 4; ++i) {
                float val = nv - 2.0f * acc[i][j];
                if (val < runv[i]) { runv[i] = val; runi[i] = (unsigned)n; }
            }
        }
    }

    // Reduce across tx (16-lane groups), lowest-index tie-break (== jnp.argmin).
    #pragma unroll
    for (int off = 8; off >= 1; off >>= 1) {
        #pragma unroll
        for (int i = 0; i < 4; ++i) {
            float    ov = __shfl_xor(runv[i], off);
            unsigned oi = __shfl_xor(runi[i], off);
            if (ov < runv[i] || (ov == runv[i] && oi < runi[i])) { runv[i] = ov; runi[i] = oi; }
        }
    }
    if (tx == 0) {
        #pragma unroll
        for (int i = 0; i < 4; ++i)
            out[b * NM + m0 + ty * 4 + i] = runi[i];
    }
}

// ---------------------------------------------------------------------------
// Per-position losses. One block per position m. Mats: 0=m1, 1=nn1, 2=m2, 3=nn2.
// Produces partial sums: R (repr), S (Σ relu(1-std)), Qraw (Σ ||G||² - Σ d²).
__global__ __launch_bounds__(256)
void loss_kernel()
{
    __shared__ float Z[4 * 16 * 129];    // stride 129 kills bank conflicts
    __shared__ float red[12];
    const float* T1 = g_T[0];
    const float* T2 = g_T[1];
    const int m = blockIdx.x;
    const int t = threadIdx.x;

    #pragma unroll
    for (int i = 0; i < 8; ++i) {
        int idx = t + i * 256;           // 0..2047
        int b = idx >> 7, c = idx & 127;
        unsigned r1 = g_idx[0][b * NM + m];
        unsigned r2 = g_idx[1][b * NM + m];
        Z[0 * 2064 + b * 129 + c] = T1[((size_t)b * NM + m)  * NC + c];
        Z[1 * 2064 + b * 129 + c] = T2[((size_t)b * NM + r1) * NC + c];
        Z[2 * 2064 + b * 129 + c] = T2[((size_t)b * NM + m)  * NC + c];
        Z[3 * 2064 + b * 129 + c] = T1[((size_t)b * NM + r2) * NC + c];
    }
    __syncthreads();

    // repr loss partial (uncentered)
    float racc = 0.f;
    #pragma unroll
    for (int i = 0; i < 8; ++i) {
        int idx = t + i * 256;
        int b = idx >> 7, c = idx & 127;
        float d0 = Z[0 * 2064 + b * 129 + c] - Z[1 * 2064 + b * 129 + c];
        float d1 = Z[2 * 2064 + b * 129 + c] - Z[3 * 2064 + b * 129 + c];
        racc += d0 * d0 + d1 * d1;
    }
    __syncthreads();                     // repr reads before centering writes

    // column stats: center in place, variance, std-loss, diag² accumulation
    float sacc = 0.f, qdacc = 0.f;
    #pragma unroll
    for (int pass = 0; pass < 2; ++pass) {
        int mat = (t >> 7) + pass * 2;
        int c   = t & 127;
        float* Zm = &Z[mat * 2064];
        float mu = 0.f;
        #pragma unroll
        for (int b = 0; b < 16; ++b) mu += Zm[b * 129 + c];
        mu *= 0.0625f;
        float d = 0.f;
        #pragma unroll
        for (int b = 0; b < 16; ++b) {
            float v = Zm[b * 129 + c] - mu;
            Zm[b * 129 + c] = v;
            d += v * v;
        }
        float stdv = sqrtf(d * (1.0f / 15.0f) + 1e-4f);
        sacc  += fmaxf(1.0f - stdv, 0.f);
        qdacc += d * d;
    }
    __syncthreads();

    // 16x16 Gram per matrix: ||X^T X||_F^2 == ||X X^T||_F^2
    float qaacc = 0.f;
    const int gi = t >> 4, gj = t & 15;
    #pragma unroll
    for (int mat = 0; mat < 4; ++mat) {
        const float* Zi = &Z[mat * 2064 + gi * 129];
        const float* Zj = &Z[mat * 2064 + gj * 129];
        float g = 0.f;
        #pragma unroll 8
        for (int c = 0; c < NC; ++c) g += Zi[c] * Zj[c];
        qaacc += g * g;
    }

    // block-reduce the three partials
    float v0 = racc, v1 = sacc, v2 = qaacc - qdacc;
    #pragma unroll
    for (int off = 32; off >= 1; off >>= 1) {
        v0 += __shfl_xor(v0, off);
        v1 += __shfl_xor(v1, off);
        v2 += __shfl_xor(v2, off);
    }
    const int w = t >> 6;
    if ((t & 63) == 0) { red[w] = v0; red[4 + w] = v1; red[8 + w] = v2; }
    __syncthreads();
    if (t == 0) {
        g_part[0][m] = red[0] + red[1] + red[2] + red[3];
        g_part[1][m] = red[4] + red[5] + red[6] + red[7];
        g_part[2][m] = red[8] + red[9] + red[10] + red[11];
    }
}

// ---------------------------------------------------------------------------
__global__ __launch_bounds__(256)
void final_kernel(float* __restrict__ out)
{
    const int t = threadIdx.x;
    float r = 0.f, s = 0.f, q = 0.f;
    for (int i = t; i < NM; i += 256) {
        r += g_part[0][i];
        s += g_part[1][i];
        q += g_part[2][i];
    }
    __shared__ float red[12];
    #pragma unroll
    for (int off = 32; off >= 1; off >>= 1) {
        r += __shfl_xor(r, off);
        s += __shfl_xor(s, off);
        q += __shfl_xor(q, off);
    }
    const int w = t >> 6;
    if ((t & 63) == 0) { red[w] = r; red[4 + w] = s; red[8 + w] = q; }
    __syncthreads();
    if (t == 0) {
        r = red[0] + red[1] + red[2] + red[3];
        s = red[4] + red[5] + red[6] + red[7];
        q = red[8] + red[9] + red[10] + red[11];
        // inv = 25 * ΣR / (2 * 16*1024*128)
        out[0] = r * (25.0f / 4194304.0f);
        // var = 25 * ΣS / (4 * 1024*128)
        out[1] = s * (25.0f / 524288.0f);
        // cov = ΣQraw / (225 * 1024 * 512)
        out[2] = q * (1.0f / (225.0f * 1024.0f * 512.0f));
    }
}

// ---------------------------------------------------------------------------
extern "C" void kernel_launch(void* const* d_in, const int* in_sizes, int n_in,
                              void* d_out, int out_size, void* d_ws, size_t ws_size,
                              hipStream_t stream)
{
    const float* e1 = (const float*)d_in[0];
    const float* e2 = (const float*)d_in[1];
    float* out = (float*)d_out;

    transpose_kernel<<<dim3(16, 2, 32), 256, 0, stream>>>(e1, e2);
    norm_kernel<<<128, 256, 0, stream>>>(e1, e2);
    argmin_kernel<<<dim3(256, 2), 256, 0, stream>>>(e1, e2);
    loss_kernel<<<1024, 256, 0, stream>>>();
    final_kernel<<<1, 256, 0, stream>>>(out);
}

// Round 2
// 126.346 us; speedup vs baseline: 1.4054x; 1.4054x over previous
//
#include <hip/hip_runtime.h>
#include <hip/hip_bf16.h>
#include <math.h>

// Problem constants: B=16, C=128, M=H*W=1024.
#define NB 16
#define NC 128
#define NM 1024

// Persistent device scratch (fully rewritten every call -> deterministic).
__device__ float    g_T[2][NB * NM * NC];     // token-major copies: T[mat][b][p][c]
__device__ float    g_norm[2][NB * NM];       // ||token||^2 per matrix
__device__ unsigned g_idx[2][NB * NM];        // [0]=idx1 (NN of m1 in m2), [1]=idx2
__device__ float    g_part[3][NM];            // per-position partials: R, S, Qraw
__device__ float    g_rval[NB][4][NM];        // row-min partials over 4 col-splits
__device__ unsigned g_ridx[NB][4][NM];
__device__ float    g_cval[NB][8][NM];        // col-min partials over 8 row-tiles
__device__ unsigned g_cidx[NB][8][NM];

// ---------------------------------------------------------------------------
// Transpose E[b][c][p] (c-major) -> T[b][p][c] (token-major), both matrices.
__global__ __launch_bounds__(256)
void transpose_kernel(const float* __restrict__ e1, const float* __restrict__ e2)
{
    __shared__ float tile[64][65];
    const int z   = blockIdx.z;
    const int b   = z >> 1;
    const int mat = z & 1;
    const float* src = mat ? e2 : e1;
    float*       dst = g_T[mat];
    const int p0 = blockIdx.x * 64;
    const int c0 = blockIdx.y * 64;
    const int tj = threadIdx.x & 63;
    const int ti = threadIdx.x >> 6;     // 0..3
    const float* sb = src + (size_t)b * NC * NM;
    #pragma unroll
    for (int i = 0; i < 16; ++i) {
        int c = i * 4 + ti;
        tile[c][tj] = sb[(size_t)(c0 + c) * NM + p0 + tj];
    }
    __syncthreads();
    float* db = dst + (size_t)b * NM * NC;
    #pragma unroll
    for (int i = 0; i < 16; ++i) {
        int p = i * 4 + ti;
        db[(size_t)(p0 + p) * NC + c0 + tj] = tile[tj][p];
    }
}

// ---------------------------------------------------------------------------
// Token norms directly from the c-major layout (coalesced over p).
__global__ __launch_bounds__(256)
void norm_kernel(const float* __restrict__ e1, const float* __restrict__ e2)
{
    const int z   = blockIdx.x;
    const int mat = z >> 6;
    const int b   = (z >> 2) & 15;
    const int pc  = z & 3;
    const float* src = mat ? e2 : e1;
    const int p = pc * 256 + threadIdx.x;
    const float* sb = src + (size_t)b * NC * NM + p;
    float s = 0.f;
    #pragma unroll 4
    for (int c = 0; c < NC; ++c) {
        float v = sb[(size_t)c * NM];
        s += v * v;
    }
    g_norm[mat][b * NM + p] = s;
}

// ---------------------------------------------------------------------------
// Shared-S argmin: compute dot(m1[m], m2[n]) tiles ONCE, derive
//   row direction: min over n of nB[n] - 2S  -> idx1 partial (per col-split)
//   col direction: min over m of nA[m] - 2S  -> idx2 partial (per row-tile)
// Tile: 128 rows x 256 cols (2 n-tiles of 128), 8x8 micro-tile, k chunks of 64.
// LDS layout [k][row] / [k][col]; micro quads split as {q*4, 64+q*4} so each
// ds_read_b128 spreads over 8 bank-groups (2-way = free).
__global__ __launch_bounds__(256, 2)
void argmin2_kernel(const float* __restrict__ e1, const float* __restrict__ e2)
{
    __shared__ float lA[64 * 128];
    __shared__ float lB[64 * 128];
    __shared__ float    s_cv[4][128];
    __shared__ unsigned s_ci[4][128];

    const int blk = blockIdx.x;          // 512 = 16b * 8rt * 4cs
    const int b  = blk >> 5;
    const int rt = (blk >> 2) & 7;
    const int cs = blk & 3;
    const int m0 = rt << 7;
    const int n0 = cs << 8;
    const int t  = threadIdx.x;
    const int tx = t & 15, ty = t >> 4;

    const float* Ab = e1 + (size_t)b * NC * NM;
    const float* Bb = e2 + (size_t)b * NC * NM;
    const float* nA = &g_norm[0][b * NM];   // ||m1||^2 (for col direction)
    const float* nB = &g_norm[1][b * NM];   // ||m2||^2 (for row direction)

    // this thread's 8 local row indices and their norms
    float rn[8];
    #pragma unroll
    for (int i = 0; i < 8; ++i) {
        int r = (i < 4) ? (ty * 4 + i) : (64 + ty * 4 + i - 4);
        rn[i] = nA[m0 + r];
    }

    float rv[8]; unsigned ri[8];
    #pragma unroll
    for (int i = 0; i < 8; ++i) { rv[i] = 3.4e38f; ri[i] = 0u; }

    for (int nt = 0; nt < 2; ++nt) {
        const int nbase = n0 + nt * 128;
        float acc[8][8] = {};
        for (int kc = 0; kc < 2; ++kc) {
            __syncthreads();             // protect lA/lB (and s_cv from prev nt)
            #pragma unroll
            for (int i = 0; i < 8; ++i) {
                int idx = t + i * 256;               // 0..2047 float4-chunks
                int k = idx >> 5, rq = (idx & 31) * 4;
                float4 va = *reinterpret_cast<const float4*>(Ab + (size_t)(kc * 64 + k) * NM + m0 + rq);
                float4 vb = *reinterpret_cast<const float4*>(Bb + (size_t)(kc * 64 + k) * NM + nbase + rq);
                *reinterpret_cast<float4*>(&lA[k * 128 + rq]) = va;
                *reinterpret_cast<float4*>(&lB[k * 128 + rq]) = vb;
            }
            __syncthreads();
            #pragma unroll 4
            for (int k = 0; k < 64; ++k) {
                float4 a0 = *reinterpret_cast<const float4*>(&lA[k * 128 + ty * 4]);
                float4 a1 = *reinterpret_cast<const float4*>(&lA[k * 128 + 64 + ty * 4]);
                float4 b0 = *reinterpret_cast<const float4*>(&lB[k * 128 + tx * 4]);
                float4 b1 = *reinterpret_cast<const float4*>(&lB[k * 128 + 64 + tx * 4]);
                float a8[8] = {a0.x, a0.y, a0.z, a0.w, a1.x, a1.y, a1.z, a1.w};
                float b8[8] = {b0.x, b0.y, b0.z, b0.w, b1.x, b1.y, b1.z, b1.w};
                #pragma unroll
                for (int i = 0; i < 8; ++i)
                    #pragma unroll
                    for (int j = 0; j < 8; ++j)
                        acc[i][j] += a8[i] * b8[j];
            }
        }
        // row-min update (j ascending == n ascending within thread; strict <
        // plus idx tie-break in reductions reproduces jnp.argmin semantics)
        #pragma unroll
        for (int j = 0; j < 8; ++j) {
            int c = (j < 4) ? (tx * 4 + j) : (64 + tx * 4 + j - 4);
            int n = nbase + c;
            float nv = nB[n];
            #pragma unroll
            for (int i = 0; i < 8; ++i) {
                float val = nv - 2.0f * acc[i][j];
                if (val < rv[i]) { rv[i] = val; ri[i] = (unsigned)n; }
            }
        }
        // col-min partial for this tile (i ascending == m ascending)
        float cv[8]; unsigned ci[8];
        #pragma unroll
        for (int j = 0; j < 8; ++j) { cv[j] = 3.4e38f; ci[j] = 0u; }
        #pragma unroll
        for (int i = 0; i < 8; ++i) {
            int r = (i < 4) ? (ty * 4 + i) : (64 + ty * 4 + i - 4);
            int m = m0 + r;
            #pragma unroll
            for (int j = 0; j < 8; ++j) {
                float val = rn[i] - 2.0f * acc[i][j];
                if (val < cv[j]) { cv[j] = val; ci[j] = (unsigned)m; }
            }
        }
        // intra-wave reduce across the 4 ty-groups of this wave
        #pragma unroll
        for (int off = 16; off <= 32; off <<= 1) {
            #pragma unroll
            for (int j = 0; j < 8; ++j) {
                float    ov = __shfl_xor(cv[j], off);
                unsigned oi = __shfl_xor(ci[j], off);
                if (ov < cv[j] || (ov == cv[j] && oi < ci[j])) { cv[j] = ov; ci[j] = oi; }
            }
        }
        const int wv = t >> 6;
        if ((t & 63) < 16) {
            #pragma unroll
            for (int j = 0; j < 8; ++j) {
                int c = (j < 4) ? (tx * 4 + j) : (64 + tx * 4 + j - 4);
                s_cv[wv][c] = cv[j]; s_ci[wv][c] = ci[j];
            }
        }
        __syncthreads();
        if (t < 128) {
            float v = s_cv[0][t]; unsigned id = s_ci[0][t];
            #pragma unroll
            for (int w = 1; w < 4; ++w) {
                float ov = s_cv[w][t]; unsigned oi = s_ci[w][t];
                if (ov < v || (ov == v && oi < id)) { v = ov; id = oi; }
            }
            g_cval[b][rt][nbase + t] = v;
            g_cidx[b][rt][nbase + t] = id;
        }
        // next iteration's first __syncthreads protects s_cv / lA / lB reuse
    }
    // row-min reduce across tx (16-lane groups)
    #pragma unroll
    for (int off = 8; off >= 1; off >>= 1) {
        #pragma unroll
        for (int i = 0; i < 8; ++i) {
            float    ov = __shfl_xor(rv[i], off);
            unsigned oi = __shfl_xor(ri[i], off);
            if (ov < rv[i] || (ov == rv[i] && oi < ri[i])) { rv[i] = ov; ri[i] = oi; }
        }
    }
    if (tx == 0) {
        #pragma unroll
        for (int i = 0; i < 8; ++i) {
            int r = (i < 4) ? (ty * 4 + i) : (64 + ty * 4 + i - 4);
            g_rval[b][cs][m0 + r] = rv[i];
            g_ridx[b][cs][m0 + r] = ri[i];
        }
    }
}

// ---------------------------------------------------------------------------
// Combine the 4 col-split partials per (b, m) -> idx1. cs ascending = n ranges
// ascending, strict < + idx tie-break keeps lowest n.
__global__ __launch_bounds__(256)
void rowmin_kernel()
{
    int gid = blockIdx.x * 256 + threadIdx.x;   // 16384 = 16*1024
    int b = gid >> 10, m = gid & 1023;
    float v = g_rval[b][0][m]; unsigned id = g_ridx[b][0][m];
    #pragma unroll
    for (int cs = 1; cs < 4; ++cs) {
        float ov = g_rval[b][cs][m]; unsigned oi = g_ridx[b][cs][m];
        if (ov < v || (ov == v && oi < id)) { v = ov; id = oi; }
    }
    g_idx[0][b * NM + m] = id;
}

// Combine the 8 row-tile partials per (b, n) -> idx2.
__global__ __launch_bounds__(256)
void colmin_kernel()
{
    int gid = blockIdx.x * 256 + threadIdx.x;
    int b = gid >> 10, n = gid & 1023;
    float v = g_cval[b][0][n]; unsigned id = g_cidx[b][0][n];
    #pragma unroll
    for (int rt = 1; rt < 8; ++rt) {
        float ov = g_cval[b][rt][n]; unsigned oi = g_cidx[b][rt][n];
        if (ov < v || (ov == v && oi < id)) { v = ov; id = oi; }
    }
    g_idx[1][b * NM + n] = id;
}

// ---------------------------------------------------------------------------
// Per-position losses. One block per position m. Mats: 0=m1, 1=nn1, 2=m2, 3=nn2.
__global__ __launch_bounds__(256)
void loss_kernel()
{
    __shared__ float Z[4 * 16 * 129];    // stride 129 kills bank conflicts
    __shared__ float red[12];
    const float* T1 = g_T[0];
    const float* T2 = g_T[1];
    const int m = blockIdx.x;
    const int t = threadIdx.x;

    #pragma unroll
    for (int i = 0; i < 8; ++i) {
        int idx = t + i * 256;           // 0..2047
        int b = idx >> 7, c = idx & 127;
        unsigned r1 = g_idx[0][b * NM + m];
        unsigned r2 = g_idx[1][b * NM + m];
        Z[0 * 2064 + b * 129 + c] = T1[((size_t)b * NM + m)  * NC + c];
        Z[1 * 2064 + b * 129 + c] = T2[((size_t)b * NM + r1) * NC + c];
        Z[2 * 2064 + b * 129 + c] = T2[((size_t)b * NM + m)  * NC + c];
        Z[3 * 2064 + b * 129 + c] = T1[((size_t)b * NM + r2) * NC + c];
    }
    __syncthreads();

    // repr loss partial (uncentered)
    float racc = 0.f;
    #pragma unroll
    for (int i = 0; i < 8; ++i) {
        int idx = t + i * 256;
        int b = idx >> 7, c = idx & 127;
        float d0 = Z[0 * 2064 + b * 129 + c] - Z[1 * 2064 + b * 129 + c];
        float d1 = Z[2 * 2064 + b * 129 + c] - Z[3 * 2064 + b * 129 + c];
        racc += d0 * d0 + d1 * d1;
    }
    __syncthreads();                     // repr reads before centering writes

    // column stats: center in place, variance, std-loss, diag² accumulation
    float sacc = 0.f, qdacc = 0.f;
    #pragma unroll
    for (int pass = 0; pass < 2; ++pass) {
        int mat = (t >> 7) + pass * 2;
        int c   = t & 127;
        float* Zm = &Z[mat * 2064];
        float mu = 0.f;
        #pragma unroll
        for (int b = 0; b < 16; ++b) mu += Zm[b * 129 + c];
        mu *= 0.0625f;
        float d = 0.f;
        #pragma unroll
        for (int b = 0; b < 16; ++b) {
            float v = Zm[b * 129 + c] - mu;
            Zm[b * 129 + c] = v;
            d += v * v;
        }
        float stdv = sqrtf(d * (1.0f / 15.0f) + 1e-4f);
        sacc  += fmaxf(1.0f - stdv, 0.f);
        qdacc += d * d;
    }
    __syncthreads();

    // 16x16 Gram per matrix: ||X^T X||_F^2 == ||X X^T||_F^2
    float qaacc = 0.f;
    const int gi = t >> 4, gj = t & 15;
    #pragma unroll
    for (int mat = 0; mat < 4; ++mat) {
        const float* Zi = &Z[mat * 2064 + gi * 129];
        const float* Zj = &Z[mat * 2064 + gj * 129];
        float g = 0.f;
        #pragma unroll 8
        for (int c = 0; c < NC; ++c) g += Zi[c] * Zj[c];
        qaacc += g * g;
    }

    // block-reduce the three partials
    float v0 = racc, v1 = sacc, v2 = qaacc - qdacc;
    #pragma unroll
    for (int off = 32; off >= 1; off >>= 1) {
        v0 += __shfl_xor(v0, off);
        v1 += __shfl_xor(v1, off);
        v2 += __shfl_xor(v2, off);
    }
    const int w = t >> 6;
    if ((t & 63) == 0) { red[w] = v0; red[4 + w] = v1; red[8 + w] = v2; }
    __syncthreads();
    if (t == 0) {
        g_part[0][m] = red[0] + red[1] + red[2] + red[3];
        g_part[1][m] = red[4] + red[5] + red[6] + red[7];
        g_part[2][m] = red[8] + red[9] + red[10] + red[11];
    }
}

// ---------------------------------------------------------------------------
__global__ __launch_bounds__(256)
void final_kernel(float* __restrict__ out)
{
    const int t = threadIdx.x;
    float r = 0.f, s = 0.f, q = 0.f;
    for (int i = t; i < NM; i += 256) {
        r += g_part[0][i];
        s += g_part[1][i];
        q += g_part[2][i];
    }
    __shared__ float red[12];
    #pragma unroll
    for (int off = 32; off >= 1; off >>= 1) {
        r += __shfl_xor(r, off);
        s += __shfl_xor(s, off);
        q += __shfl_xor(q, off);
    }
    const int w = t >> 6;
    if ((t & 63) == 0) { red[w] = r; red[4 + w] = s; red[8 + w] = q; }
    __syncthreads();
    if (t == 0) {
        r = red[0] + red[1] + red[2] + red[3];
        s = red[4] + red[5] + red[6] + red[7];
        q = red[8] + red[9] + red[10] + red[11];
        out[0] = r * (25.0f / 4194304.0f);
        out[1] = s * (25.0f / 524288.0f);
        out[2] = q * (1.0f / (225.0f * 1024.0f * 512.0f));
    }
}

// ---------------------------------------------------------------------------
extern "C" void kernel_launch(void* const* d_in, const int* in_sizes, int n_in,
                              void* d_out, int out_size, void* d_ws, size_t ws_size,
                              hipStream_t stream)
{
    const float* e1 = (const float*)d_in[0];
    const float* e2 = (const float*)d_in[1];
    float* out = (float*)d_out;

    transpose_kernel<<<dim3(16, 2, 32), 256, 0, stream>>>(e1, e2);
    norm_kernel<<<128, 256, 0, stream>>>(e1, e2);
    argmin2_kernel<<<512, 256, 0, stream>>>(e1, e2);
    rowmin_kernel<<<64, 256, 0, stream>>>();
    colmin_kernel<<<64, 256, 0, stream>>>();
    loss_kernel<<<1024, 256, 0, stream>>>();
    final_kernel<<<1, 256, 0, stream>>>(out);
}